// Round 8
// baseline (474.387 us; speedup 1.0000x reference)
//
#include <hip/hip_runtime.h>
#include <math.h>

#define T 2048
#define HID 4096
#define NH 32
#define NKV 8
#define HD 128
#define QSCALE 0.08838834764831845f   // 1/sqrt(128)

typedef __attribute__((ext_vector_type(8))) short short8;
typedef __attribute__((ext_vector_type(4))) float f32x4;
typedef __attribute__((ext_vector_type(16))) float f32x16;

static __device__ __forceinline__ unsigned short f2bf(float f) {
  union { float f; unsigned u; } v; v.f = f;
  unsigned r = v.u;
  r += 0x7fffu + ((r >> 16) & 1u);   // round-to-nearest-even
  return (unsigned short)(r >> 16);
}

// async 16B/lane global->LDS DMA; LDS dest is wave-uniform base + lane*16
static __device__ __forceinline__ void async_cp16(const unsigned short* g, unsigned short* l) {
  __builtin_amdgcn_global_load_lds(
      (const __attribute__((address_space(1))) void*)g,
      (__attribute__((address_space(3))) void*)l,
      16, 0, 0);
}

#define SCHED0 __builtin_amdgcn_sched_barrier(0)
#define VMCNT(n) asm volatile("s_waitcnt vmcnt(" #n ")" ::: "memory")

// ---------------- fused cast fp32 -> bf16 for x, Wq, Wk, Wv ----------------
__global__ __launch_bounds__(256) void cast4_kernel(const float* __restrict__ s0, const float* __restrict__ s1,
                                                    const float* __restrict__ s2, const float* __restrict__ s3,
                                                    unsigned short* __restrict__ d0, unsigned short* __restrict__ d1,
                                                    unsigned short* __restrict__ d2, unsigned short* __restrict__ d3,
                                                    int n0, int n1, int n2, int n3) {
  int i = blockIdx.x * 256 + threadIdx.x;
  const float* s; unsigned short* d; int j = i;
  if (j < n0) { s = s0; d = d0; }
  else { j -= n0;
    if (j < n1) { s = s1; d = d1; }
    else { j -= n1;
      if (j < n2) { s = s2; d = d2; }
      else { j -= n2;
        if (j >= n3) return;
        s = s3; d = d3; } } }
  float4 f = ((const float4*)s)[j];
  ushort4 o;
  o.x = f2bf(f.x); o.y = f2bf(f.y); o.z = f2bf(f.z); o.w = f2bf(f.w);
  ((ushort4*)d)[j] = o;
}

// ---------------- single-window 256xBN GEMM (m97-structure at full-fill geometry) ----------------
// C[M,N] fp32 = A[M,K]bf16 * Bt[N,K]bf16^T. 512 threads = 8 waves (4M x 2N),
// wave-tile 64x(NF*32), 16x16x32 MFMA, BK=64, double-buffered LDS.
// KEY (r8): per K-tile ONE barrier-delimited region containing ALL ds_reads AND
// all MFMAs — no lgkmcnt(0), no sched pinning, no setprio. Compiler emits
// progressive counted lgkmcnt (m97-proven), wave skew overlaps LDS drain with
// MFMA across waves. 2 barriers/K-tile (vs 6 in the phase-split gemm9).
// Stage(t+1) issued before counted vmcnt -> stage(t) confirmed, t+1 in flight.
// Swizzle: 16B slot ^= (row&7) on pre-swizzled source + ds_read (0 conflicts).

static __device__ __forceinline__ short8 ldfrag(const unsigned short* tile, int row0, int ks, int lane) {
  // row0 multiple of 16 so row&7 == lane&7
  int row = row0 + (lane & 15);
  int slot = (ks * 4 + (lane >> 4)) ^ (lane & 7);
  return *(const short8*)&tile[row * 64 + slot * 8];
}

template <int NF>
__global__ __launch_bounds__(512, 1) void gemm11(const unsigned short* __restrict__ A,
                                                 const unsigned short* __restrict__ Bt,
                                                 float* __restrict__ C,
                                                 int M, int N, int K) {
  constexpr int NB = 2 * NF;               // 16-col B-frags per wave
  __shared__ __align__(16) unsigned short As[2][16384];      // 2 x 256x64
  __shared__ __align__(16) unsigned short Bs[2][NF * 4096];  // 2 x (NF*64)x64
  int tid = threadIdx.x, wave = tid >> 6, lane = tid & 63;
  int wm = wave >> 1, wn = wave & 1;
  long bm0 = (long)blockIdx.y * 256, bn0 = (long)blockIdx.x * (NF * 64);
  int ar = wm * 64, br = wn * (NF * 32);

  // loop-invariant stage base pointers (swizzled source offset folded in)
  long stRow = wave * 8 + (lane >> 3);
  int slot = ((lane & 7) ^ (lane >> 3)) * 8;
  const unsigned short* baseA[4];
#pragma unroll
  for (int c = 0; c < 4; c++) baseA[c] = A + (bm0 + c * 64 + stRow) * (long)K + slot;
  const unsigned short* baseB[NF];
#pragma unroll
  for (int c = 0; c < NF; c++) baseB[c] = Bt + (bn0 + c * 64 + stRow) * (long)K + slot;

  int nkt = K >> 6;
  f32x4 acc[4][NB] = {};

  // prologue: stage tile0 -> buf0
#pragma unroll
  for (int c = 0; c < 4; c++) async_cp16(baseA[c], &As[0][c * 4096 + wave * 512]);
#pragma unroll
  for (int c = 0; c < NF; c++) async_cp16(baseB[c], &Bs[0][c * 4096 + wave * 512]);

#pragma unroll 1
  for (int t = 0; t < nkt; ++t) {
    // stage tile t+1 into opposite buffer (its last reads finished before the
    // closing barrier of window t-1, which precedes this issue)
    int tn = (t + 1 < nkt) ? (t + 1) : (nkt - 1);   // tail: dead restage, never read
    int kn = tn << 6;
#pragma unroll
    for (int c = 0; c < 4; c++) async_cp16(baseA[c] + kn, &As[(t + 1) & 1][c * 4096 + wave * 512]);
#pragma unroll
    for (int c = 0; c < NF; c++) async_cp16(baseB[c] + kn, &Bs[(t + 1) & 1][c * 4096 + wave * 512]);
    if constexpr (NF == 3) { VMCNT(7); } else { VMCNT(6); }   // stage(t) landed; t+1 in flight
    SCHED0; __builtin_amdgcn_s_barrier(); SCHED0;

    // ---- single region: all reads + all MFMAs (compiler pipelines via counted lgkm)
    const unsigned short* as = As[t & 1];
    const unsigned short* bs = Bs[t & 1];
    short8 a[4][2], b[NB][2];
#pragma unroll
    for (int m = 0; m < 4; m++)
#pragma unroll
      for (int ks = 0; ks < 2; ks++) a[m][ks] = ldfrag(as, ar + m * 16, ks, lane);
#pragma unroll
    for (int n = 0; n < NB; n++)
#pragma unroll
      for (int ks = 0; ks < 2; ks++) b[n][ks] = ldfrag(bs, br + n * 16, ks, lane);
#pragma unroll
    for (int ks = 0; ks < 2; ks++)
#pragma unroll
      for (int m = 0; m < 4; m++)
#pragma unroll
        for (int n = 0; n < NB; n++)
          acc[m][n] = __builtin_amdgcn_mfma_f32_16x16x32_bf16(a[m][ks], b[n][ks], acc[m][n], 0, 0, 0);
    SCHED0; __builtin_amdgcn_s_barrier(); SCHED0;   // all reads(t) retired before next re-stage
  }
  VMCNT(0);   // drain tail dead stage before endpgm

  // epilogue: 16x16 C/D layout: col = lane&15, row = (lane>>4)*4 + j
#pragma unroll
  for (int m = 0; m < 4; m++)
#pragma unroll
    for (int n = 0; n < NB; n++) {
      long row = bm0 + ar + m * 16 + ((lane >> 4) << 2);
      long col = bn0 + br + n * 16 + (lane & 15);
#pragma unroll
      for (int j = 0; j < 4; j++)
        C[(row + j) * (long)N + col] = acc[m][n][j];
    }
}

// ---------------- merged aux: RoPE + V-transpose + Wo cast (one dispatch) ----------------
// runs after QKV GEMM; wqkv_bf is dead there, so Wo cast reuses it safely.
// grid: [0,20480) rope (512 x 40), [20480,21504) transpose_v (32x4x8), [21504,37888) Wo cast.
__global__ __launch_bounds__(256) void aux_kernel(const float* __restrict__ qkvf,
                                                  unsigned short* __restrict__ qb,
                                                  unsigned short* __restrict__ kb,
                                                  unsigned short* __restrict__ vtb,
                                                  const float* __restrict__ Wo,
                                                  unsigned short* __restrict__ wo_bf) {
  __shared__ float tile[64][33];
  int b = blockIdx.x;
  if (b < 20480) {
    // ---- RoPE (llama3 scaling); 4 t per block
    int bx = b & 511, hh = b >> 9;
    int lt = threadIdx.x >> 6, d = threadIdx.x & 63;
    int t = bx * 4 + lt;
    float ex = (float)d * (1.0f / 64.0f);
    float inv = expf(-ex * 13.122363377404328f);           // 500000^(-d/64)
    float wl = 6.283185307179586f / inv;
    float inv_s;
    if (wl > 8192.0f)       inv_s = inv * 0.125f;
    else if (wl < 2048.0f)  inv_s = inv;
    else {
      float smooth = (8192.0f / wl - 1.0f) * (1.0f / 3.0f);
      inv_s = (1.0f - smooth) * 0.125f * inv + smooth * inv;
    }
    float ang = (float)t * inv_s;
    float s, c;
    sincosf(ang, &s, &c);
    if (hh < NH) {
      const float* base = qkvf + (long)t * 6144 + hh * HD;
      float lo = base[d], hi = base[d + 64];
      long o = ((long)hh * T + t) * HD;
      qb[o + d]      = f2bf((lo * c - hi * s) * QSCALE);
      qb[o + d + 64] = f2bf((hi * c + lo * s) * QSCALE);
    } else {
      int h = hh - NH;
      const float* base = qkvf + (long)t * 6144 + 4096 + h * HD;
      float lo = base[d], hi = base[d + 64];
      long o = ((long)h * T + t) * HD;
      kb[o + d]      = f2bf(lo * c - hi * s);
      kb[o + d + 64] = f2bf(hi * c + lo * s);
    }
  } else if (b < 21504) {
    // ---- V transpose: qkvf[t][5120 + h*128+d] fp32 -> [h][d][t] bf16
    int b2 = b - 20480;
    int t0 = (b2 & 31) * 64, d0 = ((b2 >> 5) & 3) * 32, h = b2 >> 7;
    int tid = threadIdx.x;
    int dd = tid & 31, tt = tid >> 5;
#pragma unroll
    for (int i = 0; i < 8; i++) {
      int t = tt + i * 8;
      tile[t][dd] = qkvf[(long)(t0 + t) * 6144 + 5120 + h * HD + d0 + dd];
    }
    __syncthreads();
    int t2 = tid & 63, d2 = tid >> 6;
#pragma unroll
    for (int i = 0; i < 8; i++) {
      int d = d2 + i * 4;
      vtb[((long)(h * HD + d0 + d)) * T + t0 + t2] = f2bf(tile[t2][d]);
    }
  } else {
    // ---- Wo fp32 -> bf16 (4 floats/thread)
    int j = (b - 21504) * 256 + threadIdx.x;   // j < HID*HID/4 exactly
    float4 f = ((const float4*)Wo)[j];
    ushort4 o;
    o.x = f2bf(f.x); o.y = f2bf(f.y); o.z = f2bf(f.z); o.w = f2bf(f.w);
    ((ushort4*)wo_bf)[j] = o;
  }
}

// ---------------- flash attention, causal, GQA (r5-proven, frozen) ----------------
// QBLK=128, 2 blocks/CU + complementary causal pairing (load-bearing — r6 showed
// 1-block/CU QBLK=256 regresses from causal imbalance). K/V double-buffered with
// 1-tile lookahead + counted vmcnt(8). LDS 80 KB exactly.
__global__ __launch_bounds__(256, 2) void attn_kernel(const unsigned short* __restrict__ qb,
                                                      const unsigned short* __restrict__ kbuf,
                                                      const unsigned short* __restrict__ vtb,
                                                      unsigned short* __restrict__ ob) {
  __shared__ __align__(16) unsigned short Ks[2][64 * 128];   // [key][d], groups XOR row&15
  __shared__ __align__(16) unsigned short Vs[2][128 * 64];   // [d][key], groups XOR row&7
  __shared__ __align__(16) unsigned short Ps[4][32 * 64];    // per-wave P, XOR (row&7)<<3
  int h = blockIdx.y;
  int kvh = h >> 2;
  // complementary causal workload pairing for co-resident blocks
  int qt = (blockIdx.y >= 16) ? (int)(gridDim.x - 1 - blockIdx.x) : (int)blockIdx.x;
  int q0 = qt * 128;
  int tid = threadIdx.x, wave = tid >> 6, lane = tid & 63;
  int l31 = lane & 31, half = lane >> 5;
  const unsigned short* Kb = kbuf + (long)kvh * T * HD;  // [t][d]
  const unsigned short* Vb = vtb + (long)kvh * HD * T;   // [d][t]

  // per-tile K/V stage into buffer bf (8 cp16/wave)
  auto STAGE = [&](int tile, int bf) {
    int kb0 = tile * 64;
#pragma unroll
    for (int i = 0; i < 4; i++) {
      int c = wave * 4 + i;
      { int row = c * 4 + (lane >> 4);
        int g = (lane & 15) ^ (row & 15);
        async_cp16(&Kb[(long)(kb0 + row) * HD + g * 8], &Ks[bf][c * 512]); }
      { int row = c * 8 + (lane >> 3);
        int g = (lane & 7) ^ (row & 7);
        async_cp16(&Vb[(long)row * T + kb0 + g * 8], &Vs[bf][c * 512]); }
    }
  };

  STAGE(0, 0);   // tile0 in flight

  // Q A-frags (32x32x16 layout: m=lane&31, k=half*8+j)
  int qrow = q0 + wave * 32 + l31;
  short8 aq[8];
#pragma unroll
  for (int ks = 0; ks < 8; ks++)
    aq[ks] = *(const short8*)&qb[((long)h * T + qrow) * HD + ks * 16 + half * 8];

  f32x16 oacc[4] = {};
  float psum[16];
#pragma unroll
  for (int r = 0; r < 16; r++) psum[r] = 0.0f;

  int ntiles = 2 * qt + 2;
  for (int tile = 0; tile < ntiles; tile++) {
    int cur = tile & 1;
    if (tile + 1 < ntiles) {
      STAGE(tile + 1, cur ^ 1);                    // lookahead into opposite buffer
      asm volatile("s_waitcnt vmcnt(8)" ::: "memory");  // stage(tile) landed; (tile+1) in flight
    } else {
      asm volatile("s_waitcnt vmcnt(0)" ::: "memory");  // last tile: drain
    }
    SCHED0; __builtin_amdgcn_s_barrier(); SCHED0;

    // S = Q K^T : 32q x 64key per wave
    f32x16 sacc[2] = {};
#pragma unroll
    for (int ks = 0; ks < 8; ks++)
#pragma unroll
      for (int nt = 0; nt < 2; nt++) {
        int row = nt * 32 + l31;
        short8 bk = *(const short8*)&Ks[cur][row * 128 + (((2 * ks + half) ^ (row & 15)) * 8)];
        sacc[nt] = __builtin_amdgcn_mfma_f32_32x32x16_bf16(aq[ks], bk, sacc[nt], 0, 0, 0);
      }

    // causal mask (wave-uniform branch)
    int kb0 = tile * 64;
    if (kb0 + 63 > q0 + wave * 32) {
#pragma unroll
      for (int nt = 0; nt < 2; nt++) {
        int key = kb0 + nt * 32 + l31;
#pragma unroll
        for (int r = 0; r < 16; r++) {
          int qr = q0 + wave * 32 + (r & 3) + 8 * (r >> 2) + 4 * half;
          if (key > qr) sacc[nt][r] = -3.0e38f;
        }
      }
    }

    // p = exp(s); per-lane partial row sums; pack P to LDS (stride 64, XOR swizzle)
#pragma unroll
    for (int nt = 0; nt < 2; nt++)
#pragma unroll
      for (int r = 0; r < 16; r++) {
        float p = __expf(sacc[nt][r]);
        psum[r] += p;
        int prow = (r & 3) + 8 * (r >> 2) + 4 * half;
        Ps[wave][prow * 64 + ((nt * 32 + l31) ^ ((prow & 7) << 3))] = f2bf(p);
      }

    // O += P V
#pragma unroll
    for (int ks = 0; ks < 4; ks++) {
      short8 ap = *(const short8*)&Ps[wave][l31 * 64 + (((ks * 2 + half) ^ (l31 & 7)) * 8)];
#pragma unroll
      for (int nt = 0; nt < 4; nt++) {
        int row = nt * 32 + l31;
        short8 bv = *(const short8*)&Vs[cur][row * 64 + (((2 * ks + half) ^ (row & 7)) * 8)];
        oacc[nt] = __builtin_amdgcn_mfma_f32_32x32x16_bf16(ap, bv, oacc[nt], 0, 0, 0);
      }
    }
    SCHED0; __builtin_amdgcn_s_barrier(); SCHED0;   // protects buf[cur] before re-stage
  }

  // end-of-kernel row-sum reduction (within each 32-lane half)
#pragma unroll
  for (int off = 1; off <= 16; off <<= 1)
#pragma unroll
    for (int r = 0; r < 16; r++)
      psum[r] += __shfl_xor(psum[r], off, 64);

#pragma unroll
  for (int nt = 0; nt < 4; nt++)
#pragma unroll
    for (int r = 0; r < 16; r++) {
      int row = q0 + wave * 32 + (r & 3) + 8 * (r >> 2) + 4 * half;
      ob[(long)row * HID + h * HD + nt * 32 + l31] = f2bf(oacc[nt][r] / psum[r]);
    }
}

extern "C" void kernel_launch(void* const* d_in, const int* in_sizes, int n_in,
                              void* d_out, int out_size, void* d_ws, size_t ws_size,
                              hipStream_t stream) {
  const float* x  = (const float*)d_in[0];
  const float* Wq = (const float*)d_in[1];
  const float* Wk = (const float*)d_in[2];
  const float* Wv = (const float*)d_in[3];
  const float* Wo = (const float*)d_in[4];
  float* out = (float*)d_out;

  char* ws = (char*)d_ws;
  size_t off = 0;
  auto alloc = [&](size_t bytes) {
    char* p = ws + off;
    off += (bytes + 255) & ~(size_t)255;
    return p;
  };
  unsigned short* x_bf    = (unsigned short*)alloc((size_t)T * HID * 2);
  unsigned short* wqkv_bf = (unsigned short*)alloc((size_t)6144 * HID * 2); // Wq++Wk++Wv; reused for Wo
  float* qkvf = (float*)alloc((size_t)T * 6144 * 4);                        // Q ++ K ++ V fused (fp32)
  unsigned short* qb  = (unsigned short*)alloc((size_t)NH * T * HD * 2);
  unsigned short* kbb = (unsigned short*)alloc((size_t)NKV * T * HD * 2);
  unsigned short* vtb = (unsigned short*)alloc((size_t)NKV * HD * T * 2);
  unsigned short* obb = (unsigned short*)alloc((size_t)T * HID * 2);

  // fused cast of x, Wq, Wk, Wv (one dispatch)
  int n0 = T * HID / 4, n1 = HID * HID / 4, n2 = 1024 * HID / 4, n3 = 1024 * HID / 4;
  int ntot = n0 + n1 + n2 + n3;
  cast4_kernel<<<dim3((ntot + 255) / 256), dim3(256), 0, stream>>>(
      x, Wq, Wk, Wv,
      x_bf, wqkv_bf, wqkv_bf + (size_t)HID * HID, wqkv_bf + (size_t)5120 * HID,
      n0, n1, n2, n3);

  // fused QKV projection: C[2048,6144] fp32 — BN=192, grid 32x8 = 256 blocks (full fill)
  gemm11<3><<<dim3(6144 / 192, T / 256), dim3(512), 0, stream>>>(x_bf, wqkv_bf, qkvf, T, 6144, HID);

  // merged RoPE + V-transpose + Wo cast (wqkv_bf dead after QKV -> safe reuse)
  aux_kernel<<<dim3(37888), dim3(256), 0, stream>>>(qkvf, qb, kbb, vtb, Wo, wqkv_bf);

  attn_kernel<<<dim3(T / 128, NH), dim3(256), 0, stream>>>(qb, kbb, vtb, obb);
  // output projection: BN=128, grid 32x8 = 256 blocks (full fill)
  gemm11<2><<<dim3(HID / 128, T / 256), dim3(512), 0, stream>>>(obb, wqkv_bf, out, T, HID, HID);
}

// Round 9
// 441.874 us; speedup vs baseline: 1.0736x; 1.0736x over previous
//
#include <hip/hip_runtime.h>
#include <math.h>

#define T 2048
#define HID 4096
#define NH 32
#define NKV 8
#define HD 128
#define QSCALE 0.08838834764831845f   // 1/sqrt(128)

typedef __attribute__((ext_vector_type(8))) short short8;
typedef __attribute__((ext_vector_type(4))) float f32x4;
typedef __attribute__((ext_vector_type(16))) float f32x16;

static __device__ __forceinline__ unsigned short f2bf(float f) {
  union { float f; unsigned u; } v; v.f = f;
  unsigned r = v.u;
  r += 0x7fffu + ((r >> 16) & 1u);   // round-to-nearest-even
  return (unsigned short)(r >> 16);
}

// async 16B/lane global->LDS DMA; LDS dest is wave-uniform base + lane*16
static __device__ __forceinline__ void async_cp16(const unsigned short* g, unsigned short* l) {
  __builtin_amdgcn_global_load_lds(
      (const __attribute__((address_space(1))) void*)g,
      (__attribute__((address_space(3))) void*)l,
      16, 0, 0);
}

#define SCHED0 __builtin_amdgcn_sched_barrier(0)
#define VMCNT(n) asm volatile("s_waitcnt vmcnt(" #n ")" ::: "memory")

// ---------------- fused cast fp32 -> bf16 for x, Wq, Wk, Wv ----------------
__global__ __launch_bounds__(256) void cast4_kernel(const float* __restrict__ s0, const float* __restrict__ s1,
                                                    const float* __restrict__ s2, const float* __restrict__ s3,
                                                    unsigned short* __restrict__ d0, unsigned short* __restrict__ d1,
                                                    unsigned short* __restrict__ d2, unsigned short* __restrict__ d3,
                                                    int n0, int n1, int n2, int n3) {
  int i = blockIdx.x * 256 + threadIdx.x;
  const float* s; unsigned short* d; int j = i;
  if (j < n0) { s = s0; d = d0; }
  else { j -= n0;
    if (j < n1) { s = s1; d = d1; }
    else { j -= n1;
      if (j < n2) { s = s2; d = d2; }
      else { j -= n2;
        if (j >= n3) return;
        s = s3; d = d3; } } }
  float4 f = ((const float4*)s)[j];
  ushort4 o;
  o.x = f2bf(f.x); o.y = f2bf(f.y); o.z = f2bf(f.z); o.w = f2bf(f.w);
  ((ushort4*)d)[j] = o;
}

// ---------------- balanced-phase 256xBN GEMM (r3-proven, frozen at its ceiling) ----------------
// Six structural variants (m97-128², 8-phase-256², fill-exact, balanced, pipelined-read,
// single-window) all land 110-120 µs: per K-tile LDS-read drain (1927 cyc) and MFMA
// (1862 cyc) serialize under barrier lockstep; wave-tile 64x96 sits at the 40 FLOP/B
// LDS/MFMA balance point, so time = sum ≈ 103 µs. This variant is the best measured.

static __device__ __forceinline__ short8 ldfrag(const unsigned short* tile, int row0, int ks, int lane) {
  // row0 multiple of 16 so row&7 == lane&7
  int row = row0 + (lane & 15);
  int slot = (ks * 4 + (lane >> 4)) ^ (lane & 7);
  return *(const short8*)&tile[row * 64 + slot * 8];
}

static __device__ __forceinline__ void ldb2(short8 (&b)[2][2], const unsigned short* bs, int br0, int lane) {
#pragma unroll
  for (int j = 0; j < 2; j++)
#pragma unroll
    for (int ks = 0; ks < 2; ks++)
      b[j][ks] = ldfrag(bs, br0 + j * 16, ks, lane);
}

template <int H>  // pre-read A-frag half: m = 2H, 2H+1
static __device__ __forceinline__ void preA(short8 (&a)[4][2], const unsigned short* as, int ar, int lane) {
#pragma unroll
  for (int m = 2 * H; m < 2 * H + 2; m++)
#pragma unroll
    for (int ks = 0; ks < 2; ks++)
      a[m][ks] = ldfrag(as, ar + m * 16, ks, lane);
}

// 16 MFMA on n-pair P; ks outermost so same-acc dependent pairs are 8 issues apart
template <int P, int NF>
static __device__ __forceinline__ void mfma16(const short8 (&a)[4][2], const short8 (&b)[2][2],
                                              f32x4 (&acc)[4][2 * NF]) {
  __builtin_amdgcn_s_setprio(1);
#pragma unroll
  for (int ks = 0; ks < 2; ks++)
#pragma unroll
    for (int m = 0; m < 4; m++)
#pragma unroll
      for (int j = 0; j < 2; j++)
        acc[m][P * 2 + j] = __builtin_amdgcn_mfma_f32_16x16x32_bf16(
            a[m][ks], b[j][ks], acc[m][P * 2 + j], 0, 0, 0);
  __builtin_amdgcn_s_setprio(0);
}

#define BAR_PRE  do { SCHED0; __builtin_amdgcn_s_barrier(); \
                      asm volatile("s_waitcnt lgkmcnt(0)" ::: "memory"); SCHED0; } while (0)
#define BAR_POST do { SCHED0; __builtin_amdgcn_s_barrier(); SCHED0; } while (0)

// one K-tile: aC = this tile's A-frags (already in regs), aN = next tile's (filled here)
template <int NF>
static __device__ __forceinline__ void tile_body(
    short8 (&aC)[4][2], short8 (&aN)[4][2],
    const unsigned short* bsRd, unsigned short* bsSt,
    const unsigned short* asN, unsigned short* asS,
    const unsigned short* const (&baseA)[4], const unsigned short* const (&baseB)[NF],
    int kA, int kB, int ar, int br, int wave, int lane,
    f32x4 (&acc)[4][2 * NF]) {
  short8 b[2][2];
  if constexpr (NF == 3) {
    // PhA: b-pair0 (4 reads); stage B(t+1) x3 -> bsSt
    ldb2(b, bsRd, br + 0, lane);
    async_cp16(baseB[0] + kB, bsSt + 0 * 4096 + wave * 512);
    async_cp16(baseB[1] + kB, bsSt + 1 * 4096 + wave * 512);
    async_cp16(baseB[2] + kB, bsSt + 2 * 4096 + wave * 512);
    BAR_PRE; mfma16<0, NF>(aC, b, acc); BAR_POST;
    // PhB: b-pair1 + pre-read aN half0 (8 reads); stage A(t+3) c0,c1 -> asS
    ldb2(b, bsRd, br + 32, lane);
    preA<0>(aN, asN, ar, lane);
    async_cp16(baseA[0] + kA, asS + 0 * 4096 + wave * 512);
    async_cp16(baseA[1] + kA, asS + 1 * 4096 + wave * 512);
    BAR_PRE; mfma16<1, NF>(aC, b, acc); BAR_POST;
    // PhC: b-pair2 + pre-read aN half1 (8 reads); stage A(t+3) c2,c3; vmcnt(4)
    ldb2(b, bsRd, br + 64, lane);
    preA<1>(aN, asN, ar, lane);
    async_cp16(baseA[2] + kA, asS + 2 * 4096 + wave * 512);
    async_cp16(baseA[3] + kA, asS + 3 * 4096 + wave * 512);
    VMCNT(4);   // drains A(t+2) + B(t+1); leaves A(t+3) x4 in flight
    BAR_PRE; mfma16<2, NF>(aC, b, acc); BAR_POST;
  } else {
    // PhA: b-pair0 + pre-read aN half0 (8 reads); stage B(t+2) x2 -> bsSt
    ldb2(b, bsRd, br + 0, lane);
    preA<0>(aN, asN, ar, lane);
    async_cp16(baseB[0] + kB, bsSt + 0 * 4096 + wave * 512);
    async_cp16(baseB[1] + kB, bsSt + 1 * 4096 + wave * 512);
    BAR_PRE; mfma16<0, NF>(aC, b, acc); BAR_POST;
    // PhB: b-pair1 + pre-read aN half1 (8 reads); stage A(t+3) x4 -> asS; vmcnt(6)
    ldb2(b, bsRd, br + 32, lane);
    preA<1>(aN, asN, ar, lane);
    async_cp16(baseA[0] + kA, asS + 0 * 4096 + wave * 512);
    async_cp16(baseA[1] + kA, asS + 1 * 4096 + wave * 512);
    async_cp16(baseA[2] + kA, asS + 2 * 4096 + wave * 512);
    async_cp16(baseA[3] + kA, asS + 3 * 4096 + wave * 512);
    VMCNT(6);   // drains A(t+2); leaves B(t+2) x2 + A(t+3) x4 in flight
    BAR_PRE; mfma16<1, NF>(aC, b, acc); BAR_POST;
  }
}

template <int NF>
__global__ __launch_bounds__(512, 2) void gemm9(const unsigned short* __restrict__ A,
                                                const unsigned short* __restrict__ Bt,
                                                float* __restrict__ C,
                                                int M, int N, int K) {
  __shared__ __align__(16) unsigned short AsBuf[3][16384];                   // 3 x 256x64 (96 KB)
  __shared__ __align__(16) unsigned short BsBuf[NF == 3 ? 2 : 3][NF * 4096]; // 48 KB either way
  int tid = threadIdx.x, wave = tid >> 6, lane = tid & 63;
  int wm = wave >> 1, wn = wave & 1;
  long bm0 = (long)blockIdx.y * 256, bn0 = (long)blockIdx.x * (NF * 64);
  int ar = wm * 64, br = wn * (NF * 32);

  // loop-invariant stage base pointers (swizzled source offset folded in)
  long stRow = wave * 8 + (lane >> 3);
  int slot = ((lane & 7) ^ (lane >> 3)) * 8;
  const unsigned short* baseA[4];
#pragma unroll
  for (int c = 0; c < 4; c++) baseA[c] = A + (bm0 + c * 64 + stRow) * (long)K + slot;
  const unsigned short* baseB[NF];
#pragma unroll
  for (int c = 0; c < NF; c++) baseB[c] = Bt + (bn0 + c * 64 + stRow) * (long)K + slot;

  int nkt = K >> 6;
  f32x4 acc[4][2 * NF] = {};
  short8 aX[4][2], aY[4][2];
  unsigned short *as0 = AsBuf[0], *as1 = AsBuf[1], *as2 = AsBuf[2];

  if constexpr (NF == 3) {
    // prologue: B(0)->Bs0, A(0)->as0, A(1)->as1, A(2)->as2
#pragma unroll
    for (int c = 0; c < 3; c++) async_cp16(baseB[c], &BsBuf[0][c * 4096 + wave * 512]);
#pragma unroll
    for (int c = 0; c < 4; c++) async_cp16(baseA[c], as0 + c * 4096 + wave * 512);
#pragma unroll
    for (int c = 0; c < 4; c++) async_cp16(baseA[c] + 64, as1 + c * 4096 + wave * 512);
#pragma unroll
    for (int c = 0; c < 4; c++) async_cp16(baseA[c] + 128, as2 + c * 4096 + wave * 512);
    VMCNT(4);   // B(0),A(0),A(1) landed; A(2) in flight
    SCHED0; __builtin_amdgcn_s_barrier(); SCHED0;
    preA<0>(aX, as0, ar, lane); preA<1>(aX, as0, ar, lane);
#pragma unroll 1
    for (int it = 0; it < (nkt >> 1); ++it) {
      int t = 2 * it;
      int kA0 = ((t + 3) < nkt ? (t + 3) : (nkt - 1)) << 6;
      int kB0 = ((t + 1) < nkt ? (t + 1) : (nkt - 1)) << 6;
      tile_body<3>(aX, aY, BsBuf[0], BsBuf[1], as1, as0, baseA, baseB, kA0, kB0, ar, br, wave, lane, acc);
      int kA1 = ((t + 4) < nkt ? (t + 4) : (nkt - 1)) << 6;
      int kB1 = ((t + 2) < nkt ? (t + 2) : (nkt - 1)) << 6;
      tile_body<3>(aY, aX, BsBuf[1], BsBuf[0], as2, as1, baseA, baseB, kA1, kB1, ar, br, wave, lane, acc);
      unsigned short* tA = as0; as0 = as2; as2 = as1; as1 = tA;
    }
  } else {
    unsigned short *bs0 = BsBuf[0], *bs1 = BsBuf[1], *bs2 = BsBuf[2];
    // prologue: B(0)->bs0, A(0)->as0, B(1)->bs1, A(1)->as1, A(2)->as2
#pragma unroll
    for (int c = 0; c < 2; c++) async_cp16(baseB[c], bs0 + c * 4096 + wave * 512);
#pragma unroll
    for (int c = 0; c < 4; c++) async_cp16(baseA[c], as0 + c * 4096 + wave * 512);
#pragma unroll
    for (int c = 0; c < 2; c++) async_cp16(baseB[c] + 64, bs1 + c * 4096 + wave * 512);
#pragma unroll
    for (int c = 0; c < 4; c++) async_cp16(baseA[c] + 64, as1 + c * 4096 + wave * 512);
#pragma unroll
    for (int c = 0; c < 4; c++) async_cp16(baseA[c] + 128, as2 + c * 4096 + wave * 512);
    VMCNT(4);   // B(0),A(0),B(1),A(1) landed; A(2) in flight
    SCHED0; __builtin_amdgcn_s_barrier(); SCHED0;
    preA<0>(aX, as0, ar, lane); preA<1>(aX, as0, ar, lane);
#pragma unroll 1
    for (int it = 0; it < (nkt >> 1); ++it) {
      int t = 2 * it;
      int kA0 = ((t + 3) < nkt ? (t + 3) : (nkt - 1)) << 6;
      int kB0 = ((t + 2) < nkt ? (t + 2) : (nkt - 1)) << 6;
      tile_body<2>(aX, aY, bs0, bs2, as1, as0, baseA, baseB, kA0, kB0, ar, br, wave, lane, acc);
      int kA1 = ((t + 4) < nkt ? (t + 4) : (nkt - 1)) << 6;
      int kB1 = ((t + 3) < nkt ? (t + 3) : (nkt - 1)) << 6;
      tile_body<2>(aY, aX, bs1, bs0, as2, as1, baseA, baseB, kA1, kB1, ar, br, wave, lane, acc);
      unsigned short* tA = as0; as0 = as2; as2 = as1; as1 = tA;
      unsigned short* tB = bs0; bs0 = bs2; bs2 = bs1; bs1 = tB;
    }
  }
  VMCNT(0);   // drain tail stages before endpgm

  // epilogue: 16x16 C/D layout: col = lane&15, row = (lane>>4)*4 + j
#pragma unroll
  for (int m = 0; m < 4; m++)
#pragma unroll
    for (int n = 0; n < 2 * NF; n++) {
      long row = bm0 + ar + m * 16 + ((lane >> 4) << 2);
      long col = bn0 + br + n * 16 + (lane & 15);
#pragma unroll
      for (int j = 0; j < 4; j++)
        C[(row + j) * (long)N + col] = acc[m][n][j];
    }
}

// ---------------- merged aux: RoPE + V-transpose + Wo cast (one dispatch) ----------------
// runs after QKV GEMM; wqkv_bf is dead there, so Wo cast reuses it safely.
// grid: [0,20480) rope (512 x 40), [20480,21504) transpose_v (32x4x8), [21504,37888) Wo cast.
__global__ __launch_bounds__(256) void aux_kernel(const float* __restrict__ qkvf,
                                                  unsigned short* __restrict__ qb,
                                                  unsigned short* __restrict__ kb,
                                                  unsigned short* __restrict__ vtb,
                                                  const float* __restrict__ Wo,
                                                  unsigned short* __restrict__ wo_bf) {
  __shared__ float tile[64][33];
  int b = blockIdx.x;
  if (b < 20480) {
    // ---- RoPE (llama3 scaling); 4 t per block
    int bx = b & 511, hh = b >> 9;
    int lt = threadIdx.x >> 6, d = threadIdx.x & 63;
    int t = bx * 4 + lt;
    float ex = (float)d * (1.0f / 64.0f);
    float inv = expf(-ex * 13.122363377404328f);           // 500000^(-d/64)
    float wl = 6.283185307179586f / inv;
    float inv_s;
    if (wl > 8192.0f)       inv_s = inv * 0.125f;
    else if (wl < 2048.0f)  inv_s = inv;
    else {
      float smooth = (8192.0f / wl - 1.0f) * (1.0f / 3.0f);
      inv_s = (1.0f - smooth) * 0.125f * inv + smooth * inv;
    }
    float ang = (float)t * inv_s;
    float s, c;
    sincosf(ang, &s, &c);
    if (hh < NH) {
      const float* base = qkvf + (long)t * 6144 + hh * HD;
      float lo = base[d], hi = base[d + 64];
      long o = ((long)hh * T + t) * HD;
      qb[o + d]      = f2bf((lo * c - hi * s) * QSCALE);
      qb[o + d + 64] = f2bf((hi * c + lo * s) * QSCALE);
    } else {
      int h = hh - NH;
      const float* base = qkvf + (long)t * 6144 + 4096 + h * HD;
      float lo = base[d], hi = base[d + 64];
      long o = ((long)h * T + t) * HD;
      kb[o + d]      = f2bf(lo * c - hi * s);
      kb[o + d + 64] = f2bf(hi * c + lo * s);
    }
  } else if (b < 21504) {
    // ---- V transpose: qkvf[t][5120 + h*128+d] fp32 -> [h][d][t] bf16
    int b2 = b - 20480;
    int t0 = (b2 & 31) * 64, d0 = ((b2 >> 5) & 3) * 32, h = b2 >> 7;
    int tid = threadIdx.x;
    int dd = tid & 31, tt = tid >> 5;
#pragma unroll
    for (int i = 0; i < 8; i++) {
      int t = tt + i * 8;
      tile[t][dd] = qkvf[(long)(t0 + t) * 6144 + 5120 + h * HD + d0 + dd];
    }
    __syncthreads();
    int t2 = tid & 63, d2 = tid >> 6;
#pragma unroll
    for (int i = 0; i < 8; i++) {
      int d = d2 + i * 4;
      vtb[((long)(h * HD + d0 + d)) * T + t0 + t2] = f2bf(tile[t2][d]);
    }
  } else {
    // ---- Wo fp32 -> bf16 (4 floats/thread)
    int j = (b - 21504) * 256 + threadIdx.x;   // j < HID*HID/4 exactly
    float4 f = ((const float4*)Wo)[j];
    ushort4 o;
    o.x = f2bf(f.x); o.y = f2bf(f.y); o.z = f2bf(f.z); o.w = f2bf(f.w);
    ((ushort4*)wo_bf)[j] = o;
  }
}

// ---------------- flash attention, causal, GQA (r5 structure + T5 setprio) ----------------
// QBLK=128, 2 blocks/CU + complementary causal pairing (load-bearing — r6 showed
// 1-block/CU QBLK=256 regresses from causal imbalance). K/V double-buffered with
// 1-tile lookahead + counted vmcnt(8). LDS 80 KB exactly.
// r9: s_setprio(1) around QK and PV MFMA clusters (T5; m191 regime: co-resident
// blocks at different causal depths give the CU scheduler role diversity).
__global__ __launch_bounds__(256, 2) void attn_kernel(const unsigned short* __restrict__ qb,
                                                      const unsigned short* __restrict__ kbuf,
                                                      const unsigned short* __restrict__ vtb,
                                                      unsigned short* __restrict__ ob) {
  __shared__ __align__(16) unsigned short Ks[2][64 * 128];   // [key][d], groups XOR row&15
  __shared__ __align__(16) unsigned short Vs[2][128 * 64];   // [d][key], groups XOR row&7
  __shared__ __align__(16) unsigned short Ps[4][32 * 64];    // per-wave P, XOR (row&7)<<3
  int h = blockIdx.y;
  int kvh = h >> 2;
  // complementary causal workload pairing for co-resident blocks
  int qt = (blockIdx.y >= 16) ? (int)(gridDim.x - 1 - blockIdx.x) : (int)blockIdx.x;
  int q0 = qt * 128;
  int tid = threadIdx.x, wave = tid >> 6, lane = tid & 63;
  int l31 = lane & 31, half = lane >> 5;
  const unsigned short* Kb = kbuf + (long)kvh * T * HD;  // [t][d]
  const unsigned short* Vb = vtb + (long)kvh * HD * T;   // [d][t]

  // per-tile K/V stage into buffer bf (8 cp16/wave)
  auto STAGE = [&](int tile, int bf) {
    int kb0 = tile * 64;
#pragma unroll
    for (int i = 0; i < 4; i++) {
      int c = wave * 4 + i;
      { int row = c * 4 + (lane >> 4);
        int g = (lane & 15) ^ (row & 15);
        async_cp16(&Kb[(long)(kb0 + row) * HD + g * 8], &Ks[bf][c * 512]); }
      { int row = c * 8 + (lane >> 3);
        int g = (lane & 7) ^ (row & 7);
        async_cp16(&Vb[(long)row * T + kb0 + g * 8], &Vs[bf][c * 512]); }
    }
  };

  STAGE(0, 0);   // tile0 in flight

  // Q A-frags (32x32x16 layout: m=lane&31, k=half*8+j)
  int qrow = q0 + wave * 32 + l31;
  short8 aq[8];
#pragma unroll
  for (int ks = 0; ks < 8; ks++)
    aq[ks] = *(const short8*)&qb[((long)h * T + qrow) * HD + ks * 16 + half * 8];

  f32x16 oacc[4] = {};
  float psum[16];
#pragma unroll
  for (int r = 0; r < 16; r++) psum[r] = 0.0f;

  int ntiles = 2 * qt + 2;
  for (int tile = 0; tile < ntiles; tile++) {
    int cur = tile & 1;
    if (tile + 1 < ntiles) {
      STAGE(tile + 1, cur ^ 1);                    // lookahead into opposite buffer
      asm volatile("s_waitcnt vmcnt(8)" ::: "memory");  // stage(tile) landed; (tile+1) in flight
    } else {
      asm volatile("s_waitcnt vmcnt(0)" ::: "memory");  // last tile: drain
    }
    SCHED0; __builtin_amdgcn_s_barrier(); SCHED0;

    // S = Q K^T : 32q x 64key per wave (T5: boost priority through MFMA cluster)
    f32x16 sacc[2] = {};
    __builtin_amdgcn_s_setprio(1);
#pragma unroll
    for (int ks = 0; ks < 8; ks++)
#pragma unroll
      for (int nt = 0; nt < 2; nt++) {
        int row = nt * 32 + l31;
        short8 bk = *(const short8*)&Ks[cur][row * 128 + (((2 * ks + half) ^ (row & 15)) * 8)];
        sacc[nt] = __builtin_amdgcn_mfma_f32_32x32x16_bf16(aq[ks], bk, sacc[nt], 0, 0, 0);
      }
    __builtin_amdgcn_s_setprio(0);

    // causal mask (wave-uniform branch)
    int kb0 = tile * 64;
    if (kb0 + 63 > q0 + wave * 32) {
#pragma unroll
      for (int nt = 0; nt < 2; nt++) {
        int key = kb0 + nt * 32 + l31;
#pragma unroll
        for (int r = 0; r < 16; r++) {
          int qr = q0 + wave * 32 + (r & 3) + 8 * (r >> 2) + 4 * half;
          if (key > qr) sacc[nt][r] = -3.0e38f;
        }
      }
    }

    // p = exp(s); per-lane partial row sums; pack P to LDS (stride 64, XOR swizzle)
#pragma unroll
    for (int nt = 0; nt < 2; nt++)
#pragma unroll
      for (int r = 0; r < 16; r++) {
        float p = __expf(sacc[nt][r]);
        psum[r] += p;
        int prow = (r & 3) + 8 * (r >> 2) + 4 * half;
        Ps[wave][prow * 64 + ((nt * 32 + l31) ^ ((prow & 7) << 3))] = f2bf(p);
      }

    // O += P V (T5: boost priority through MFMA cluster)
    __builtin_amdgcn_s_setprio(1);
#pragma unroll
    for (int ks = 0; ks < 4; ks++) {
      short8 ap = *(const short8*)&Ps[wave][l31 * 64 + (((ks * 2 + half) ^ (l31 & 7)) * 8)];
#pragma unroll
      for (int nt = 0; nt < 4; nt++) {
        int row = nt * 32 + l31;
        short8 bv = *(const short8*)&Vs[cur][row * 64 + (((2 * ks + half) ^ (row & 7)) * 8)];
        oacc[nt] = __builtin_amdgcn_mfma_f32_32x32x16_bf16(ap, bv, oacc[nt], 0, 0, 0);
      }
    }
    __builtin_amdgcn_s_setprio(0);
    SCHED0; __builtin_amdgcn_s_barrier(); SCHED0;   // protects buf[cur] before re-stage
  }

  // end-of-kernel row-sum reduction (within each 32-lane half)
#pragma unroll
  for (int off = 1; off <= 16; off <<= 1)
#pragma unroll
    for (int r = 0; r < 16; r++)
      psum[r] += __shfl_xor(psum[r], off, 64);

#pragma unroll
  for (int nt = 0; nt < 4; nt++)
#pragma unroll
    for (int r = 0; r < 16; r++) {
      int row = q0 + wave * 32 + (r & 3) + 8 * (r >> 2) + 4 * half;
      ob[(long)row * HID + h * HD + nt * 32 + l31] = f2bf(oacc[nt][r] / psum[r]);
    }
}

extern "C" void kernel_launch(void* const* d_in, const int* in_sizes, int n_in,
                              void* d_out, int out_size, void* d_ws, size_t ws_size,
                              hipStream_t stream) {
  const float* x  = (const float*)d_in[0];
  const float* Wq = (const float*)d_in[1];
  const float* Wk = (const float*)d_in[2];
  const float* Wv = (const float*)d_in[3];
  const float* Wo = (const float*)d_in[4];
  float* out = (float*)d_out;

  char* ws = (char*)d_ws;
  size_t off = 0;
  auto alloc = [&](size_t bytes) {
    char* p = ws + off;
    off += (bytes + 255) & ~(size_t)255;
    return p;
  };
  unsigned short* x_bf    = (unsigned short*)alloc((size_t)T * HID * 2);
  unsigned short* wqkv_bf = (unsigned short*)alloc((size_t)6144 * HID * 2); // Wq++Wk++Wv; reused for Wo
  float* qkvf = (float*)alloc((size_t)T * 6144 * 4);                        // Q ++ K ++ V fused (fp32)
  unsigned short* qb  = (unsigned short*)alloc((size_t)NH * T * HD * 2);
  unsigned short* kbb = (unsigned short*)alloc((size_t)NKV * T * HD * 2);
  unsigned short* vtb = (unsigned short*)alloc((size_t)NKV * HD * T * 2);
  unsigned short* obb = (unsigned short*)alloc((size_t)T * HID * 2);

  // fused cast of x, Wq, Wk, Wv (one dispatch)
  int n0 = T * HID / 4, n1 = HID * HID / 4, n2 = 1024 * HID / 4, n3 = 1024 * HID / 4;
  int ntot = n0 + n1 + n2 + n3;
  cast4_kernel<<<dim3((ntot + 255) / 256), dim3(256), 0, stream>>>(
      x, Wq, Wk, Wv,
      x_bf, wqkv_bf, wqkv_bf + (size_t)HID * HID, wqkv_bf + (size_t)5120 * HID,
      n0, n1, n2, n3);

  // fused QKV projection: C[2048,6144] fp32 — BN=192, grid 32x8 = 256 blocks (full fill)
  gemm9<3><<<dim3(6144 / 192, T / 256), dim3(512), 0, stream>>>(x_bf, wqkv_bf, qkvf, T, 6144, HID);

  // merged RoPE + V-transpose + Wo cast (wqkv_bf dead after QKV -> safe reuse)
  aux_kernel<<<dim3(37888), dim3(256), 0, stream>>>(qkvf, qb, kbb, vtb, Wo, wqkv_bf);

  attn_kernel<<<dim3(T / 128, NH), dim3(256), 0, stream>>>(qb, kbb, vtb, obb);
  // output projection: BN=128, grid 32x8 = 256 blocks (full fill)
  gemm9<2><<<dim3(HID / 128, T / 256), dim3(512), 0, stream>>>(obb, wqkv_bf, out, T, HID, HID);
}